// Round 8
// baseline (78.599 us; speedup 1.0000x reference)
//
#include <hip/hip_runtime.h>

#define BLK 256
#define NJ 24
#define G 8
#define NG (NJ / G)
#define REP 8   // DIAGNOSTIC: repeat compute phase to expose it in counters

__global__ __launch_bounds__(BLK, 2)
void fk_kernel(const float* __restrict__ angles,   // (B, 24)
               const float* __restrict__ Torg,     // (24, 4, 4) row-major
               const float* __restrict__ axes,     // (24, 3)
               float* __restrict__ out,            // (B, 75)
               int B)
{
    __shared__ float stage[BLK * 75];
    __shared__ float sQK[NJ * 8];   // per joint: {qw,qx,qy,qz, otx,oty,otz, pad}
    __shared__ float sAx[NJ * 4];   // axis xyz + pad

    const int tid = threadIdx.x;

    // --- One-time: convert T_org rotations to quaternions (threads 0..23) ---
    if (tid < NJ) {
        const float* o = Torg + tid * 16;
        const float m00=o[0], m01=o[1], m02=o[2];
        const float m10=o[4], m11=o[5], m12=o[6];
        const float m20=o[8], m21=o[9], m22=o[10];
        const float tr = m00 + m11 + m22;
        float qw, qx, qy, qz;
        if (tr > 0.f) {
            const float S = sqrtf(tr + 1.f) * 2.f;
            qw = 0.25f * S;
            qx = (m21 - m12) / S;
            qy = (m02 - m20) / S;
            qz = (m10 - m01) / S;
        } else if (m00 > m11 && m00 > m22) {
            const float S = sqrtf(1.f + m00 - m11 - m22) * 2.f;
            qw = (m21 - m12) / S;
            qx = 0.25f * S;
            qy = (m01 + m10) / S;
            qz = (m02 + m20) / S;
        } else if (m11 > m22) {
            const float S = sqrtf(1.f + m11 - m00 - m22) * 2.f;
            qw = (m02 - m20) / S;
            qx = (m01 + m10) / S;
            qy = 0.25f * S;
            qz = (m12 + m21) / S;
        } else {
            const float S = sqrtf(1.f + m22 - m00 - m11) * 2.f;
            qw = (m10 - m01) / S;
            qx = (m02 + m20) / S;
            qy = (m12 + m21) / S;
            qz = 0.25f * S;
        }
        float* q = &sQK[tid * 8];
        q[0] = qw; q[1] = qx; q[2] = qy; q[3] = qz;
        q[4] = o[3]; q[5] = o[7]; q[6] = o[11]; q[7] = 0.f;   // O_t
        float* ax = &sAx[tid * 4];
        ax[0] = axes[tid*3+0]; ax[1] = axes[tid*3+1]; ax[2] = axes[tid*3+2]; ax[3] = 0.f;
    }
    __syncthreads();

    const int b = blockIdx.x * BLK + tid;
    const float4* ap = reinterpret_cast<const float4*>(angles + (size_t)b * NJ);

    float* srow = &stage[tid * 75];

    // ===== DIAGNOSTIC repeat loop: 8 identical compute passes =====
    #pragma unroll 1
    for (int rep = 0; rep < REP; ++rep) {
        float4 av0 = ap[0], av1 = ap[1];
        // Launder the loaded angles so the compiler cannot CSE the whole
        // pass across repeats (rule #17: ablation-via-skip DCE hazard,
        // inverted: keep repeated work live).
        asm volatile("" : "+v"(av0.x), "+v"(av0.y), "+v"(av0.z), "+v"(av0.w),
                          "+v"(av1.x), "+v"(av1.y), "+v"(av1.z), "+v"(av1.w));

        float Qw = 1.f, Qx = 0.f, Qy = 0.f, Qz = 0.f;
        float tx = 0.f, ty = 0.f, tz = 0.f;
        srow[0] = 0.f; srow[1] = 0.f; srow[2] = 0.f;   // base_pos

        #pragma unroll 1
        for (int g = 0; g < NG; ++g) {
            float4 nv0, nv1;
            if (g + 1 < NG) { nv0 = ap[2*g + 2]; nv1 = ap[2*g + 3]; }

            float a[G];
            a[0]=av0.x; a[1]=av0.y; a[2]=av0.z; a[3]=av0.w;
            a[4]=av1.x; a[5]=av1.y; a[6]=av1.z; a[7]=av1.w;

            // --- Phase A: u_j = qO_j * q_j for 8 joints (independent) ---
            float U[G][4];
            float OT[G][3];
            #pragma unroll
            for (int u = 0; u < G; ++u) {
                const int j = g * G + u;
                const float4 qo = *reinterpret_cast<const float4*>(&sQK[j*8]);
                const float4 ot = *reinterpret_cast<const float4*>(&sQK[j*8+4]);
                const float4 ax = *reinterpret_cast<const float4*>(&sAx[j*4]);
                OT[u][0] = ot.x; OT[u][1] = ot.y; OT[u][2] = ot.z;

                const float h = 0.5f * a[u];
                const float s = __sinf(h);
                const float c = __cosf(h);
                const float bx = s * ax.x, by = s * ax.y, bz = s * ax.z;

                U[u][0] = qo.x*c  - qo.y*bx - qo.z*by - qo.w*bz;
                U[u][1] = qo.x*bx + qo.y*c  + qo.z*bz - qo.w*by;
                U[u][2] = qo.x*by - qo.y*bz + qo.z*c  + qo.w*bx;
                U[u][3] = qo.x*bz + qo.y*by - qo.z*bx + qo.w*c;
            }

            // --- Phase B: serial chain ---
            #pragma unroll
            for (int u = 0; u < G; ++u) {
                const int j = g * G + u;
                const float ox = OT[u][0], oy = OT[u][1], oz = OT[u][2];

                const float cx = Qy*oz - Qz*oy + Qw*ox;
                const float cy = Qz*ox - Qx*oz + Qw*oy;
                const float cz = Qx*oy - Qy*ox + Qw*oz;
                const float dx = Qy*cz - Qz*cy;
                const float dy = Qz*cx - Qx*cz;
                const float dz = Qx*cy - Qy*cx;
                tx = tx + ox + 2.f*dx;
                ty = ty + oy + 2.f*dy;
                tz = tz + oz + 2.f*dz;

                const float uw = U[u][0], ux = U[u][1], uy = U[u][2], uz = U[u][3];
                const float nw = Qw*uw - Qx*ux - Qy*uy - Qz*uz;
                const float nx = Qw*ux + Qx*uw + Qy*uz - Qz*uy;
                const float ny = Qw*uy - Qx*uz + Qy*uw + Qz*ux;
                const float nz = Qw*uz + Qx*uy - Qy*ux + Qz*uw;
                Qw = nw; Qx = nx; Qy = ny; Qz = nz;

                srow[3 + 3*j + 0] = tx;
                srow[3 + 3*j + 1] = ty;
                srow[3 + 3*j + 2] = tz;
            }

            av0 = nv0; av1 = nv1;
        }
    }

    __syncthreads();

    // Coalesced float4 writeout (once).
    float4* out4 = reinterpret_cast<float4*>(out + (size_t)blockIdx.x * BLK * 75);
    const float4* st4 = reinterpret_cast<const float4*>(stage);
    #pragma unroll 1
    for (int i = tid; i < BLK * 75 / 4; i += BLK) {
        out4[i] = st4[i];
    }
}

extern "C" void kernel_launch(void* const* d_in, const int* in_sizes, int n_in,
                              void* d_out, int out_size, void* d_ws, size_t ws_size,
                              hipStream_t stream) {
    const float* angles = (const float*)d_in[0];
    const float* Torg   = (const float*)d_in[1];
    const float* axes   = (const float*)d_in[2];
    float* out = (float*)d_out;

    const int B = in_sizes[0] / NJ;          // 131072
    const int grid = (B + BLK - 1) / BLK;    // 512

    fk_kernel<<<grid, BLK, 0, stream>>>(angles, Torg, axes, out, B);
}

// Round 9
// 27.002 us; speedup vs baseline: 2.9108x; 2.9108x over previous
//
#include <hip/hip_runtime.h>

#define BLK 128
#define NJ 24
#define G 8
#define NG (NJ / G)

// ---- Prep: T_org -> (quat, axis, O_t) into d_ws, once per call ----
__global__ void fk_prep(const float* __restrict__ Torg,
                        const float* __restrict__ axes,
                        float* __restrict__ cst)   // (24, 12)
{
    const int j = threadIdx.x;
    if (j >= NJ) return;
    const float* o = Torg + j * 16;
    const float m00=o[0], m01=o[1], m02=o[2];
    const float m10=o[4], m11=o[5], m12=o[6];
    const float m20=o[8], m21=o[9], m22=o[10];
    const float tr = m00 + m11 + m22;
    float qw, qx, qy, qz;
    if (tr > 0.f) {
        const float S = sqrtf(tr + 1.f) * 2.f;
        qw = 0.25f * S;
        qx = (m21 - m12) / S;
        qy = (m02 - m20) / S;
        qz = (m10 - m01) / S;
    } else if (m00 > m11 && m00 > m22) {
        const float S = sqrtf(1.f + m00 - m11 - m22) * 2.f;
        qw = (m21 - m12) / S;
        qx = 0.25f * S;
        qy = (m01 + m10) / S;
        qz = (m02 + m20) / S;
    } else if (m11 > m22) {
        const float S = sqrtf(1.f + m11 - m00 - m22) * 2.f;
        qw = (m02 - m20) / S;
        qx = (m01 + m10) / S;
        qy = 0.25f * S;
        qz = (m12 + m21) / S;
    } else {
        const float S = sqrtf(1.f + m22 - m00 - m11) * 2.f;
        qw = (m10 - m01) / S;
        qx = (m02 + m20) / S;
        qy = (m12 + m21) / S;
        qz = 0.25f * S;
    }
    float* c = cst + j * 12;
    c[0] = qw; c[1] = qx; c[2] = qy; c[3] = qz;
    c[4] = axes[j*3+0]; c[5] = axes[j*3+1]; c[6] = axes[j*3+2]; c[7] = 0.f;
    c[8] = o[3]; c[9] = o[7]; c[10] = o[11]; c[11] = 0.f;
}

__global__ __launch_bounds__(BLK, 2)
void fk_kernel(const float* __restrict__ angles,   // (B, 24)
               const float* __restrict__ cst,      // (24, 12) from fk_prep
               float* __restrict__ out,            // (B, 75)
               int B)
{
    __shared__ float stage[BLK * 75];              // 38.4 KB -> 4 blocks/CU

    const int tid = threadIdx.x;
    const int b = blockIdx.x * BLK + tid;
    const float4* ap = reinterpret_cast<const float4*>(angles + (size_t)b * NJ);

    // Running transform as quaternion Q + translation t.
    float Qw = 1.f, Qx = 0.f, Qy = 0.f, Qz = 0.f;
    float tx = 0.f, ty = 0.f, tz = 0.f;

    float* srow = &stage[tid * 75];
    srow[0] = 0.f; srow[1] = 0.f; srow[2] = 0.f;   // base_pos

    // Software-pipelined angle loads (named float4 regs only).
    float4 av0 = ap[0], av1 = ap[1];

    #pragma unroll 1
    for (int g = 0; g < NG; ++g) {
        float4 nv0, nv1;
        if (g + 1 < NG) { nv0 = ap[2*g + 2]; nv1 = ap[2*g + 3]; }

        float a[G];
        a[0]=av0.x; a[1]=av0.y; a[2]=av0.z; a[3]=av0.w;
        a[4]=av1.x; a[5]=av1.y; a[6]=av1.z; a[7]=av1.w;

        // --- Phase A: u_j = qO_j * q_j for 8 joints (independent).
        // All constants are uniform compile-time-indexed loads -> s_load,
        // SGPR operands (no LDS, no vector loads).
        float U[G][4];
        float OT[G][3];
        #pragma unroll
        for (int u = 0; u < G; ++u) {
            const int j = g * G + u;
            const float qow = cst[j*12+0], qox = cst[j*12+1];
            const float qoy = cst[j*12+2], qoz = cst[j*12+3];
            const float axx = cst[j*12+4], axy = cst[j*12+5], axz = cst[j*12+6];
            OT[u][0] = cst[j*12+8]; OT[u][1] = cst[j*12+9]; OT[u][2] = cst[j*12+10];

            const float h = 0.5f * a[u];
            const float s = __sinf(h);
            const float c = __cosf(h);
            const float bx = s * axx, by = s * axy, bz = s * axz;

            // Hamilton product U = qo * (c, bx, by, bz)
            U[u][0] = qow*c  - qox*bx - qoy*by - qoz*bz;
            U[u][1] = qow*bx + qox*c  + qoy*bz - qoz*by;
            U[u][2] = qow*by - qox*bz + qoy*c  + qoz*bx;
            U[u][3] = qow*bz + qox*by - qoy*bx + qoz*c;
        }

        // --- Phase B: serial chain, short dep path ---
        #pragma unroll
        for (int u = 0; u < G; ++u) {
            const int j = g * G + u;
            const float ox = OT[u][0], oy = OT[u][1], oz = OT[u][2];

            // t_child = t + R(Q)*O_t   (v' = v + 2*qv x (qv x v + w v))
            const float cx = Qy*oz - Qz*oy + Qw*ox;
            const float cy = Qz*ox - Qx*oz + Qw*oy;
            const float cz = Qx*oy - Qy*ox + Qw*oz;
            const float dx = Qy*cz - Qz*cy;
            const float dy = Qz*cx - Qx*cz;
            const float dz = Qx*cy - Qy*cx;
            tx = tx + ox + 2.f*dx;
            ty = ty + oy + 2.f*dy;
            tz = tz + oz + 2.f*dz;

            // Q = Q * U[u]   (Hamilton)
            const float uw = U[u][0], ux = U[u][1], uy = U[u][2], uz = U[u][3];
            const float nw = Qw*uw - Qx*ux - Qy*uy - Qz*uz;
            const float nx = Qw*ux + Qx*uw + Qy*uz - Qz*uy;
            const float ny = Qw*uy - Qx*uz + Qy*uw + Qz*ux;
            const float nz = Qw*uz + Qx*uy - Qy*ux + Qz*uw;
            Qw = nw; Qx = nx; Qy = ny; Qz = nz;

            srow[3 + 3*j + 0] = tx;
            srow[3 + 3*j + 1] = ty;
            srow[3 + 3*j + 2] = tz;
        }

        av0 = nv0; av1 = nv1;
    }

    __syncthreads();

    // Coalesced float4 writeout of the whole block's 128x75 stage.
    float4* out4 = reinterpret_cast<float4*>(out + (size_t)blockIdx.x * BLK * 75);
    const float4* st4 = reinterpret_cast<const float4*>(stage);
    #pragma unroll 1
    for (int i = tid; i < BLK * 75 / 4; i += BLK) {
        out4[i] = st4[i];
    }
}

extern "C" void kernel_launch(void* const* d_in, const int* in_sizes, int n_in,
                              void* d_out, int out_size, void* d_ws, size_t ws_size,
                              hipStream_t stream) {
    const float* angles = (const float*)d_in[0];
    const float* Torg   = (const float*)d_in[1];
    const float* axes   = (const float*)d_in[2];
    float* out = (float*)d_out;
    float* cst = (float*)d_ws;                // 24*12 floats = 1152 B

    const int B = in_sizes[0] / NJ;           // 131072
    const int grid = (B + BLK - 1) / BLK;     // 1024

    fk_prep<<<1, 64, 0, stream>>>(Torg, axes, cst);
    fk_kernel<<<grid, BLK, 0, stream>>>(angles, cst, out, B);
}